// Round 6
// baseline (329.970 us; speedup 1.0000x reference)
//
#include <hip/hip_runtime.h>

typedef unsigned short u16;
typedef unsigned int uint32;
typedef __bf16 bf16x8 __attribute__((ext_vector_type(8)));
typedef float f32x4 __attribute__((ext_vector_type(4)));

static constexpr int Gg = 64;
static constexpr int Nn = 2048;
static constexpr int Ee = 16384;
static constexpr int GN = Gg * Nn;   // 131072
static constexpr int GE = Gg * Ee;   // 1048576

__device__ __forceinline__ u16 f2u(float f) {  // round-to-nearest-even bf16
    uint32 i = __float_as_uint(f);
    uint32 r = (i + 0x7FFFu + ((i >> 16) & 1u)) >> 16;
    return (u16)r;
}
__device__ __forceinline__ float lo16f(uint32 v) { return __uint_as_float(v << 16); }
__device__ __forceinline__ float hi16f(uint32 v) { return __uint_as_float(v & 0xffff0000u); }

// ---------------- setup kernels ----------------

// per-graph LDS histogram of dst -> deg, dis, invdeg (no global atomics)
__global__ __launch_bounds__(1024) void k_hist(const int* __restrict__ ei, int* __restrict__ deg,
                                               float* __restrict__ dis, float* __restrict__ invdeg) {
    int g = blockIdx.x, t = threadIdx.x;
    __shared__ int h[2048];
    h[t] = 0; h[t + 1024] = 0;
    __syncthreads();
    #pragma unroll
    for (int k = 0; k < 16; ++k) {
        int d = ei[GE + g * Ee + k * 1024 + t];
        atomicAdd(&h[d & (Nn - 1)], 1);
    }
    __syncthreads();
    #pragma unroll
    for (int k = 0; k < 2; ++k) {
        int i = k * 1024 + t;
        int c = h[i];
        deg[(g << 11) + i] = c;
        float dd = 1.0f + (float)c;
        dis[(g << 11) + i] = rsqrtf(dd);
        invdeg[(g << 11) + i] = 1.0f / dd;
    }
}

// per-GRAPH exclusive scan over nodes -> rp[g][i] (absolute into nme, base g*Ee).
// 64 blocks (was 8 with the per-p layout) — per-graph CSR serves scatter, k_A
// and the new SpMM propx; k_start is eliminated entirely.
__global__ __launch_bounds__(1024) void k_scan_g(const int* __restrict__ deg, int* __restrict__ rp) {
    int g = blockIdx.x, t = threadIdx.x;   // 1024 threads, 2 nodes each
    int i0 = 2 * t, i1 = 2 * t + 1;
    int c0 = deg[(g << 11) + i0];
    int c1 = deg[(g << 11) + i1];
    __shared__ int ps[1024];
    ps[t] = c0 + c1; __syncthreads();
    for (int off = 1; off < 1024; off <<= 1) {
        int v = (t >= off) ? ps[t - off] : 0;
        __syncthreads();
        ps[t] += v;
        __syncthreads();
    }
    int base = g * Ee + ps[t] - (c0 + c1);
    rp[(g << 11) + i0] = base;
    rp[(g << 11) + i1] = base + c0;
}

// per-graph scatter with LDS cursors (no global atomics); nme = {src gid, cf f32}
__global__ __launch_bounds__(1024) void k_scatter(const int* __restrict__ ei, const float* __restrict__ dis,
                                                  const int* __restrict__ rp, int2* __restrict__ nme) {
    int g = blockIdx.x, t = threadIdx.x;
    __shared__ int curs[2048];
    curs[t] = rp[(g << 11) + t];
    curs[t + 1024] = rp[(g << 11) + t + 1024];
    __syncthreads();
    #pragma unroll
    for (int k = 0; k < 16; ++k) {
        int e = g * Ee + k * 1024 + t;
        int s = ei[e];          // src gid
        int d = ei[GE + e];     // dst gid
        int p = atomicAdd(&curs[d & (Nn - 1)], 1);
        nme[p] = make_int2(s, __float_as_int(dis[s] * dis[d]));
    }
}

// pack bottom half of Wm into MFMA fragment order (A-operand of transposed GEMM):
// Wtp[((ks*8+ct)*64 + l)*8 + j] = bf16(Wm[(128 + ks*32+lq*8+j)*128 + ct*16+lm]), l=lq*16+lm
__global__ void k_trans(const float* __restrict__ Wm, u16* __restrict__ Wtp) {
    int tid = blockIdx.x * 256 + threadIdx.x;   // 16384
    int j = tid & 7, l = (tid >> 3) & 63, kc = tid >> 9;
    int ks = kc >> 3, ct = kc & 7, lm = l & 15, lq = l >> 4;
    int f = ks * 32 + lq * 8 + j, c = ct * 16 + lm;
    Wtp[tid] = f2u(Wm[(128 + f) * 128 + c]);
}

// A[g] = (ce @ Wm_top) + bm, ce = (x[center]*invdeg + incident edges) @ W1 + b1
__global__ void k_A(const float* __restrict__ x, const int* __restrict__ center,
                    const float* __restrict__ invdeg, const int* __restrict__ rp,
                    const int* __restrict__ degc, const int2* __restrict__ nme,
                    const float* __restrict__ W1, const float* __restrict__ b1,
                    const float* __restrict__ Wm, const float* __restrict__ bm,
                    float* __restrict__ A) {
    int g = blockIdx.x, t = threadIdx.x;   // 128 threads
    __shared__ float cepre[128], ce[128];
    int cg = (g << 11) + center[g];
    float v = x[cg * 128 + t] * invdeg[cg];
    int p0 = rp[cg], p1 = p0 + degc[cg];
    for (int e = p0; e < p1; ++e) {          // usually empty (center has no in-edges)
        int2 m = nme[e];
        v += __int_as_float(m.y) * x[m.x * 128 + t];
    }
    cepre[t] = v; __syncthreads();
    float a = b1[t];
    #pragma unroll 8
    for (int f = 0; f < 128; ++f) a += cepre[f] * W1[f * 128 + t];
    ce[t] = a; __syncthreads();
    float o = bm[t];
    #pragma unroll 8
    for (int h = 0; h < 128; ++h) o += ce[h] * Wm[h * 128 + t];
    A[g * 128 + t] = o;
}

// ---------------- mask + y GEMM (MFMA, TRANSPOSED), packed xy ----------------
// xy row (256 u16): group k (u16[4k..4k+4)) = { y[2k], y[2k+1], x[2k], x[2k+1] } bf16
__global__ __launch_bounds__(256) void k_masky(const float* __restrict__ x,
                                               const u16* __restrict__ Wtp,
                                               const float* __restrict__ A,
                                               u16* __restrict__ xy) {
    __shared__ float sA[128];
    int t = threadIdx.x;
    int tile = blockIdx.x;            // 0..2047, 64 rows each
    int g = tile >> 5;
    if (t < 128) sA[t] = A[g * 128 + t];
    __syncthreads();

    int w = t >> 6, l = t & 63;
    int lm = l & 15, lq = l >> 4;
    int row = tile * 64 + w * 16 + lm;      // this lane's x-row
    const float* xrow = x + row * 128;
    const bf16x8* Ap = (const bf16x8*)Wtp;

    float4 xf[8];
    #pragma unroll
    for (int ks = 0; ks < 4; ++ks) {
        xf[2 * ks]     = *(const float4*)(xrow + ks * 32 + lq * 8);
        xf[2 * ks + 1] = *(const float4*)(xrow + ks * 32 + lq * 8 + 4);
    }
    union { u16 u[8]; bf16x8 v; } bf[4];
    #pragma unroll
    for (int ks = 0; ks < 4; ++ks) {
        float4 x0 = xf[2 * ks], x1 = xf[2 * ks + 1];
        bf[ks].u[0] = f2u(x0.x); bf[ks].u[1] = f2u(x0.y);
        bf[ks].u[2] = f2u(x0.z); bf[ks].u[3] = f2u(x0.w);
        bf[ks].u[4] = f2u(x1.x); bf[ks].u[5] = f2u(x1.y);
        bf[ks].u[6] = f2u(x1.z); bf[ks].u[7] = f2u(x1.w);
    }

    f32x4 acc[8] = {};
    #pragma unroll
    for (int ks = 0; ks < 4; ++ks) {
        #pragma unroll
        for (int ct = 0; ct < 8; ++ct) {
            bf16x8 a = Ap[(ks * 8 + ct) * 64 + l];
            acc[ct] = __builtin_amdgcn_mfma_f32_16x16x32_bf16(a, bf[ks].v, acc[ct], 0, 0, 0);
        }
    }

    u16* orow = xy + row * 256;
    #pragma unroll
    for (int ct = 0; ct < 8; ++ct) {
        int ch = ct * 16 + lq * 4;
        float4 xv = *(const float4*)(xrow + ch);   // L1-hot
        float y0 = fmaxf(acc[ct][0] + sA[ch + 0], 0.f) * xv.x;
        float y1 = fmaxf(acc[ct][1] + sA[ch + 1], 0.f) * xv.y;
        float y2 = fmaxf(acc[ct][2] + sA[ch + 2], 0.f) * xv.z;
        float y3 = fmaxf(acc[ct][3] + sA[ch + 3], 0.f) * xv.w;
        uint4 q;
        q.x = (uint32)f2u(y0)   | ((uint32)f2u(y1)   << 16);
        q.y = (uint32)f2u(xv.x) | ((uint32)f2u(xv.y) << 16);
        q.z = (uint32)f2u(y2)   | ((uint32)f2u(y3)   << 16);
        q.w = (uint32)f2u(xv.z) | ((uint32)f2u(xv.w) << 16);
        *(uint4*)(orow + ct * 32 + lq * 8) = q;
    }
}

// ---------------- propagation v2: LDS-staged SpMM (no L2 random gather) ----------------
// Block (p = b&7, cc = col-chunk of 16 u16, dh = dst-half). Per graph of the
// p-octet: stage its 2048-row x 32B column slice into LDS (k2-major transposed:
// plane k2 of 16B rows -> ds_read_b128 bank-start 4*src mod 32 covers all 8
// positions = minimal conflicts), then walk each dst's CSR bucket reading
// neighbor rows from LDS. Replaces the random L2/L3 gather that pinned the old
// propx at 54us (FETCH 163MB vs 77MB compulsory, all ordering fixes null).
#define EACC(d, va, vb, cf)                                              \
    aY[d][0] += (cf) * lo16f((va).x); aY[d][1] += (cf) * hi16f((va).x);  \
    aX[d][0] += (cf) * lo16f((va).y); aX[d][1] += (cf) * hi16f((va).y);  \
    aY[d][2] += (cf) * lo16f((va).z); aY[d][3] += (cf) * hi16f((va).z);  \
    aX[d][2] += (cf) * lo16f((va).w); aX[d][3] += (cf) * hi16f((va).w);  \
    aY[d][4] += (cf) * lo16f((vb).x); aY[d][5] += (cf) * hi16f((vb).x);  \
    aX[d][4] += (cf) * lo16f((vb).y); aX[d][5] += (cf) * hi16f((vb).y);  \
    aY[d][6] += (cf) * lo16f((vb).z); aY[d][7] += (cf) * hi16f((vb).z);  \
    aX[d][6] += (cf) * lo16f((vb).w); aX[d][7] += (cf) * hi16f((vb).w);

__global__ __launch_bounds__(512) void k_propx(const u16* __restrict__ xy,
                                               const float* __restrict__ invdeg,
                                               const int* __restrict__ rp,
                                               const int* __restrict__ degc,
                                               const int2* __restrict__ nme,
                                               float* __restrict__ zp) {
    __shared__ u16 sx[2 * 2048 * 8];      // 64KB: plane k2 in {0,1} x 2048 rows x 16B
    int b = blockIdx.x;
    int p = b & 7, s = b >> 3;            // s 0..31
    int cc = s & 15, dh = s >> 4;         // cc 0..15, dh 0..1
    int t = threadIdx.x;                  // 0..511

    float aY[2][8] = {}, aX[2][8] = {};

    for (int g8 = 0; g8 < 8; ++g8) {
        int graph = p * 8 + g8;
        const u16* gsrc = xy + (size_t)(graph << 11) * 256 + cc * 16;
        // stage loads issued before the barrier (fly during other waves' tail compute)
        uint4 vst[8];
        #pragma unroll
        for (int j = 0; j < 8; ++j) {
            int idx = j * 512 + t;            // 0..4095 = k2*2048 + r
            int r = idx & 2047, k2 = idx >> 11;
            vst[j] = *(const uint4*)(gsrc + r * 256 + k2 * 8);
        }
        __syncthreads();                       // previous graph's compute done
        #pragma unroll
        for (int j = 0; j < 8; ++j)
            *(uint4*)(sx + (j * 512 + t) * 8) = vst[j];   // byte (k2*2048+r)*16
        __syncthreads();

        int gb = graph << 11;
        #pragma unroll
        for (int d = 0; d < 2; ++d) {
            int i = (dh << 10) + (t << 1) + d;
            int gid = gb + i;
            {   // self term: own row from LDS, cf = invdeg
                uint4 va = *(const uint4*)(sx + i * 8);
                uint4 vb = *(const uint4*)(sx + i * 8 + 16384);
                float cf = invdeg[gid];
                EACC(d, va, vb, cf)
            }
            int j = rp[gid], jend = j + degc[gid];
            for (; j + 3 < jend; j += 4) {
                int2 m0 = nme[j], m1 = nme[j + 1], m2 = nme[j + 2], m3 = nme[j + 3];
                int s0 = (m0.x & 2047) * 8, s1 = (m1.x & 2047) * 8;
                int s2 = (m2.x & 2047) * 8, s3 = (m3.x & 2047) * 8;
                uint4 a0 = *(const uint4*)(sx + s0), b0 = *(const uint4*)(sx + s0 + 16384);
                uint4 a1 = *(const uint4*)(sx + s1), b1 = *(const uint4*)(sx + s1 + 16384);
                uint4 a2 = *(const uint4*)(sx + s2), b2 = *(const uint4*)(sx + s2 + 16384);
                uint4 a3 = *(const uint4*)(sx + s3), b3 = *(const uint4*)(sx + s3 + 16384);
                float c0 = __int_as_float(m0.y), c1 = __int_as_float(m1.y);
                float c2 = __int_as_float(m2.y), c3 = __int_as_float(m3.y);
                EACC(d, a0, b0, c0) EACC(d, a1, b1, c1)
                EACC(d, a2, b2, c2) EACC(d, a3, b3, c3)
            }
            for (; j < jend; ++j) {
                int2 m = nme[j];
                int s0 = (m.x & 2047) * 8;
                uint4 va = *(const uint4*)(sx + s0), vb = *(const uint4*)(sx + s0 + 16384);
                float cf = __int_as_float(m.y);
                EACC(d, va, vb, cf)
            }
        }
    }

    #pragma unroll
    for (int d = 0; d < 2; ++d) {
        int i = (dh << 10) + (t << 1) + d;
        float* zr = zp + (size_t)((p << 11) + i) * 256 + cc * 16;
        *(float4*)(zr)      = make_float4(aY[d][0], aY[d][1], aX[d][0], aX[d][1]);
        *(float4*)(zr + 4)  = make_float4(aY[d][2], aY[d][3], aX[d][2], aX[d][3]);
        *(float4*)(zr + 8)  = make_float4(aY[d][4], aY[d][5], aX[d][4], aX[d][5]);
        *(float4*)(zr + 12) = make_float4(aY[d][6], aY[d][7], aX[d][6], aX[d][7]);
    }
}

// ---------------- reduce partials + fused output matvecs ----------------
__global__ __launch_bounds__(256) void k_reduce(const float* __restrict__ zp,
                                                const float* __restrict__ W2, const float* __restrict__ b2,
                                                const float* __restrict__ W3, const float* __restrict__ b3,
                                                float* __restrict__ out) {
    int i = blockIdx.x;   // node 0..2046
    int t = threadIdx.x;
    __shared__ float zm[128], zxm[128];
    float s = 0.f;
    #pragma unroll
    for (int p = 0; p < 8; ++p) s += zp[(size_t)(((p << 11) + i)) * 256 + t];
    s *= (1.0f / 64.0f);
    int k = t >> 2, r = t & 3;
    if (r < 2) zm[2 * k + r] = s; else zxm[2 * k + (r - 2)] = s;
    __syncthreads();
    int cc = t & 127;
    if (t < 128) {
        float acc = b2[cc];
        #pragma unroll 8
        for (int f = 0; f < 128; ++f) acc += zm[f] * W2[f * 128 + cc];
        out[i * 128 + cc] = acc;
    } else {
        float acc = b3[cc];
        #pragma unroll 8
        for (int f = 0; f < 128; ++f) acc += (zxm[f] - zm[f]) * W3[f * 128 + cc];
        out[2047 * 128 + i * 128 + cc] = acc;
    }
}

// ---------------- launch ----------------

extern "C" void kernel_launch(void* const* d_in, const int* in_sizes, int n_in,
                              void* d_out, int out_size, void* d_ws, size_t ws_size,
                              hipStream_t stream) {
    const float* x    = (const float*)d_in[0];
    const int* ei     = (const int*)d_in[1];
    const int* center = (const int*)d_in[3];
    const float* W1 = (const float*)d_in[4];
    const float* b1 = (const float*)d_in[5];
    const float* W2 = (const float*)d_in[6];
    const float* b2 = (const float*)d_in[7];
    const float* W3 = (const float*)d_in[8];
    const float* b3 = (const float*)d_in[9];
    const float* Wm = (const float*)d_in[10];
    const float* bm = (const float*)d_in[11];
    float* out = (float*)d_out;

    char* ws = (char*)d_ws;
    int*   degc   = (int*)(ws + 0);            // 512 KB
    float* dis    = (float*)(ws + 524288);     // 512 KB
    float* invdeg = (float*)(ws + 1048576);    // 512 KB
    int*   rp     = (int*)(ws + 1572864);      // 512 KB (per-graph CSR row starts)
    float* A      = (float*)(ws + 2097152);    // 32 KB
    u16*   Wtp    = (u16*)(ws + 2129920);      // 32 KB
    int2*  nme    = (int2*)(ws + 2162688);     // 8 MB
    float* zp     = (float*)(ws + 10551296);   // 16 MB
    u16*   xy     = (u16*)(ws + 27328512);     // 67 MB  (end ~94.4 MB)

    k_hist<<<dim3(Gg), dim3(1024), 0, stream>>>(ei, degc, dis, invdeg);
    k_scan_g<<<dim3(Gg), dim3(1024), 0, stream>>>(degc, rp);
    k_scatter<<<dim3(Gg), dim3(1024), 0, stream>>>(ei, dis, rp, nme);
    k_trans<<<dim3(64), dim3(256), 0, stream>>>(Wm, Wtp);
    k_A<<<dim3(Gg), dim3(128), 0, stream>>>(x, center, invdeg, rp, degc, nme, W1, b1, Wm, bm, A);
    k_masky<<<dim3(2048), dim3(256), 0, stream>>>(x, Wtp, A, xy);
    k_propx<<<dim3(256), dim3(512), 0, stream>>>(xy, invdeg, rp, degc, nme, zp);
    k_reduce<<<dim3(Nn - 1), dim3(256), 0, stream>>>(zp, W2, b2, W3, b3, out);
}

// Round 7
// 258.842 us; speedup vs baseline: 1.2748x; 1.2748x over previous
//
#include <hip/hip_runtime.h>

typedef unsigned short u16;
typedef unsigned int uint32;
typedef __bf16 bf16x8 __attribute__((ext_vector_type(8)));
typedef float f32x4 __attribute__((ext_vector_type(4)));

static constexpr int Gg = 64;
static constexpr int Nn = 2048;
static constexpr int Ee = 16384;
static constexpr int GN = Gg * Nn;   // 131072
static constexpr int GE = Gg * Ee;   // 1048576

__device__ __forceinline__ u16 f2u(float f) {  // round-to-nearest-even bf16
    uint32 i = __float_as_uint(f);
    uint32 r = (i + 0x7FFFu + ((i >> 16) & 1u)) >> 16;
    return (u16)r;
}
__device__ __forceinline__ float lo16f(uint32 v) { return __uint_as_float(v << 16); }
__device__ __forceinline__ float hi16f(uint32 v) { return __uint_as_float(v & 0xffff0000u); }

// ---------------- setup kernels ----------------

// per-graph LDS histogram of dst -> deg, dis, invdeg (no global atomics)
__global__ __launch_bounds__(1024) void k_hist(const int* __restrict__ ei, int* __restrict__ deg,
                                               float* __restrict__ dis, float* __restrict__ invdeg) {
    int g = blockIdx.x, t = threadIdx.x;
    __shared__ int h[2048];
    h[t] = 0; h[t + 1024] = 0;
    __syncthreads();
    #pragma unroll
    for (int k = 0; k < 16; ++k) {
        int d = ei[GE + g * Ee + k * 1024 + t];
        atomicAdd(&h[d & (Nn - 1)], 1);
    }
    __syncthreads();
    #pragma unroll
    for (int k = 0; k < 2; ++k) {
        int i = k * 1024 + t;
        int c = h[i];
        deg[(g << 11) + i] = c;
        float dd = 1.0f + (float)c;
        dis[(g << 11) + i] = rsqrtf(dd);
        invdeg[(g << 11) + i] = 1.0f / dd;
    }
}

// per-GRAPH exclusive scan over nodes -> rp[g][i] (absolute into nme, base g*Ee)
__global__ __launch_bounds__(1024) void k_scan_g(const int* __restrict__ deg, int* __restrict__ rp) {
    int g = blockIdx.x, t = threadIdx.x;   // 1024 threads, 2 nodes each
    int i0 = 2 * t, i1 = 2 * t + 1;
    int c0 = deg[(g << 11) + i0];
    int c1 = deg[(g << 11) + i1];
    __shared__ int ps[1024];
    ps[t] = c0 + c1; __syncthreads();
    for (int off = 1; off < 1024; off <<= 1) {
        int v = (t >= off) ? ps[t - off] : 0;
        __syncthreads();
        ps[t] += v;
        __syncthreads();
    }
    int base = g * Ee + ps[t] - (c0 + c1);
    rp[(g << 11) + i0] = base;
    rp[(g << 11) + i1] = base + c0;
}

// per-graph scatter with LDS cursors (no global atomics); nme = {src gid, cf f32}
__global__ __launch_bounds__(1024) void k_scatter(const int* __restrict__ ei, const float* __restrict__ dis,
                                                  const int* __restrict__ rp, int2* __restrict__ nme) {
    int g = blockIdx.x, t = threadIdx.x;
    __shared__ int curs[2048];
    curs[t] = rp[(g << 11) + t];
    curs[t + 1024] = rp[(g << 11) + t + 1024];
    __syncthreads();
    #pragma unroll
    for (int k = 0; k < 16; ++k) {
        int e = g * Ee + k * 1024 + t;
        int s = ei[e];          // src gid
        int d = ei[GE + e];     // dst gid
        int p = atomicAdd(&curs[d & (Nn - 1)], 1);
        nme[p] = make_int2(s, __float_as_int(dis[s] * dis[d]));
    }
}

// pack bottom half of Wm into MFMA fragment order (A-operand of transposed GEMM):
// Wtp[((ks*8+ct)*64 + l)*8 + j] = bf16(Wm[(128 + ks*32+lq*8+j)*128 + ct*16+lm]), l=lq*16+lm
__global__ void k_trans(const float* __restrict__ Wm, u16* __restrict__ Wtp) {
    int tid = blockIdx.x * 256 + threadIdx.x;   // 16384
    int j = tid & 7, l = (tid >> 3) & 63, kc = tid >> 9;
    int ks = kc >> 3, ct = kc & 7, lm = l & 15, lq = l >> 4;
    int f = ks * 32 + lq * 8 + j, c = ct * 16 + lm;
    Wtp[tid] = f2u(Wm[(128 + f) * 128 + c]);
}

// A[g] = (ce @ Wm_top) + bm, ce = (x[center]*invdeg + incident edges) @ W1 + b1
__global__ void k_A(const float* __restrict__ x, const int* __restrict__ center,
                    const float* __restrict__ invdeg, const int* __restrict__ rp,
                    const int* __restrict__ degc, const int2* __restrict__ nme,
                    const float* __restrict__ W1, const float* __restrict__ b1,
                    const float* __restrict__ Wm, const float* __restrict__ bm,
                    float* __restrict__ A) {
    int g = blockIdx.x, t = threadIdx.x;   // 128 threads
    __shared__ float cepre[128], ce[128];
    int cg = (g << 11) + center[g];
    float v = x[cg * 128 + t] * invdeg[cg];
    int p0 = rp[cg], p1 = p0 + degc[cg];
    for (int e = p0; e < p1; ++e) {          // usually empty (center has no in-edges)
        int2 m = nme[e];
        v += __int_as_float(m.y) * x[m.x * 128 + t];
    }
    cepre[t] = v; __syncthreads();
    float a = b1[t];
    #pragma unroll 8
    for (int f = 0; f < 128; ++f) a += cepre[f] * W1[f * 128 + t];
    ce[t] = a; __syncthreads();
    float o = bm[t];
    #pragma unroll 8
    for (int h = 0; h < 128; ++h) o += ce[h] * Wm[h * 128 + t];
    A[g * 128 + t] = o;
}

// ---------------- mask + y GEMM (MFMA, TRANSPOSED), packed xy ----------------
// xy row (256 u16): group k (u16[4k..4k+4)) = { y[2k], y[2k+1], x[2k], x[2k+1] } bf16
__global__ __launch_bounds__(256) void k_masky(const float* __restrict__ x,
                                               const u16* __restrict__ Wtp,
                                               const float* __restrict__ A,
                                               u16* __restrict__ xy) {
    __shared__ float sA[128];
    int t = threadIdx.x;
    int tile = blockIdx.x;            // 0..2047, 64 rows each
    int g = tile >> 5;
    if (t < 128) sA[t] = A[g * 128 + t];
    __syncthreads();

    int w = t >> 6, l = t & 63;
    int lm = l & 15, lq = l >> 4;
    int row = tile * 64 + w * 16 + lm;      // this lane's x-row
    const float* xrow = x + row * 128;
    const bf16x8* Ap = (const bf16x8*)Wtp;

    float4 xf[8];
    #pragma unroll
    for (int ks = 0; ks < 4; ++ks) {
        xf[2 * ks]     = *(const float4*)(xrow + ks * 32 + lq * 8);
        xf[2 * ks + 1] = *(const float4*)(xrow + ks * 32 + lq * 8 + 4);
    }
    union { u16 u[8]; bf16x8 v; } bf[4];
    #pragma unroll
    for (int ks = 0; ks < 4; ++ks) {
        float4 x0 = xf[2 * ks], x1 = xf[2 * ks + 1];
        bf[ks].u[0] = f2u(x0.x); bf[ks].u[1] = f2u(x0.y);
        bf[ks].u[2] = f2u(x0.z); bf[ks].u[3] = f2u(x0.w);
        bf[ks].u[4] = f2u(x1.x); bf[ks].u[5] = f2u(x1.y);
        bf[ks].u[6] = f2u(x1.z); bf[ks].u[7] = f2u(x1.w);
    }

    f32x4 acc[8] = {};
    #pragma unroll
    for (int ks = 0; ks < 4; ++ks) {
        #pragma unroll
        for (int ct = 0; ct < 8; ++ct) {
            bf16x8 a = Ap[(ks * 8 + ct) * 64 + l];
            acc[ct] = __builtin_amdgcn_mfma_f32_16x16x32_bf16(a, bf[ks].v, acc[ct], 0, 0, 0);
        }
    }

    u16* orow = xy + row * 256;
    #pragma unroll
    for (int ct = 0; ct < 8; ++ct) {
        int ch = ct * 16 + lq * 4;
        float4 xv = *(const float4*)(xrow + ch);   // L1-hot
        float y0 = fmaxf(acc[ct][0] + sA[ch + 0], 0.f) * xv.x;
        float y1 = fmaxf(acc[ct][1] + sA[ch + 1], 0.f) * xv.y;
        float y2 = fmaxf(acc[ct][2] + sA[ch + 2], 0.f) * xv.z;
        float y3 = fmaxf(acc[ct][3] + sA[ch + 3], 0.f) * xv.w;
        uint4 q;
        q.x = (uint32)f2u(y0)   | ((uint32)f2u(y1)   << 16);
        q.y = (uint32)f2u(xv.x) | ((uint32)f2u(xv.y) << 16);
        q.z = (uint32)f2u(y2)   | ((uint32)f2u(y3)   << 16);
        q.w = (uint32)f2u(xv.z) | ((uint32)f2u(xv.w) << 16);
        *(uint4*)(orow + ct * 32 + lq * 8) = q;
    }
}

// ---------------- propagation v3: graph-major gather (L2-phased) ----------------
// Block (p = b&7 -> XCD, c = b>>3): rows i = c*4 + w of ALL 8 octet graphs,
// GRAPH LOOP OUTERMOST: every block walks g8 = 0..7 in the same order, so the
// XCD's instantaneous gather footprint is ~1 graph's xy = 1MB (fits 4MB L2).
// r5 lesson: within-bucket edge ordering can't phase the footprint — temporal
// alignment must come from the block's own loop structure. r6 lesson: no LDS
// staging (occupancy + bank conflicts + partial-line zp writes killed it);
// register accumulation over the octet keeps zp at 16MB partials.
// Per row: self term (half 0) + per-graph CSR bucket, edges split by parity
// across the two half-waves; 32 lanes x 16B = full 512B row per gather.
#define ACC8(v, cf)                                                     \
    aY0 += (cf) * lo16f((v).x); aY1 += (cf) * hi16f((v).x);             \
    aX0 += (cf) * lo16f((v).y); aX1 += (cf) * hi16f((v).y);             \
    aY2 += (cf) * lo16f((v).z); aY3 += (cf) * hi16f((v).z);             \
    aX2 += (cf) * lo16f((v).w); aX3 += (cf) * hi16f((v).w);

__global__ __launch_bounds__(256) void k_propx(const u16* __restrict__ xy,
                                               const float* __restrict__ invdeg,
                                               const int* __restrict__ rp,
                                               const int* __restrict__ degc,
                                               const int2* __restrict__ nme,
                                               float* __restrict__ zp) {
    int b = blockIdx.x;
    int p = b & 7, c = b >> 3;            // p -> XCD, c 0..511
    int t = threadIdx.x, w = t >> 6, l = t & 63;
    int half = l >> 5, cl = l & 31;
    int i = c * 4 + w;                    // dst row 0..2047
    float aY0 = 0.f, aY1 = 0.f, aY2 = 0.f, aY3 = 0.f;
    float aX0 = 0.f, aX1 = 0.f, aX2 = 0.f, aX3 = 0.f;

    for (int g8 = 0; g8 < 8; ++g8) {
        int gid = ((p * 8 + g8) << 11) + i;
        if (half == 0) {   // self term
            float cf = invdeg[gid];
            uint4 v = *(const uint4*)(xy + (size_t)gid * 256 + cl * 8);
            ACC8(v, cf)
        }
        int j = rp[gid], jend = j + degc[gid];
        for (; j + 7 < jend; j += 8) {
            int2 m0 = nme[j + half];
            int2 m1 = nme[j + 2 + half];
            int2 m2 = nme[j + 4 + half];
            int2 m3 = nme[j + 6 + half];
            uint4 v0 = *(const uint4*)(xy + (size_t)m0.x * 256 + cl * 8);
            uint4 v1 = *(const uint4*)(xy + (size_t)m1.x * 256 + cl * 8);
            uint4 v2 = *(const uint4*)(xy + (size_t)m2.x * 256 + cl * 8);
            uint4 v3 = *(const uint4*)(xy + (size_t)m3.x * 256 + cl * 8);
            float c0 = __int_as_float(m0.y), c1 = __int_as_float(m1.y);
            float c2 = __int_as_float(m2.y), c3 = __int_as_float(m3.y);
            ACC8(v0, c0) ACC8(v1, c1) ACC8(v2, c2) ACC8(v3, c3)
        }
        for (; j + 3 < jend; j += 4) {
            int2 m0 = nme[j + half];
            int2 m1 = nme[j + 2 + half];
            uint4 v0 = *(const uint4*)(xy + (size_t)m0.x * 256 + cl * 8);
            uint4 v1 = *(const uint4*)(xy + (size_t)m1.x * 256 + cl * 8);
            float c0 = __int_as_float(m0.y), c1 = __int_as_float(m1.y);
            ACC8(v0, c0) ACC8(v1, c1)
        }
        for (; j < jend; j += 2) {
            int idx = j + half;
            if (idx < jend) {
                int2 m = nme[idx];
                uint4 v = *(const uint4*)(xy + (size_t)m.x * 256 + cl * 8);
                float cf = __int_as_float(m.y);
                ACC8(v, cf)
            }
        }
    }

    aY0 += __shfl_xor(aY0, 32, 64); aY1 += __shfl_xor(aY1, 32, 64);
    aX0 += __shfl_xor(aX0, 32, 64); aX1 += __shfl_xor(aX1, 32, 64);
    aY2 += __shfl_xor(aY2, 32, 64); aY3 += __shfl_xor(aY3, 32, 64);
    aX2 += __shfl_xor(aX2, 32, 64); aX3 += __shfl_xor(aX3, 32, 64);
    if (half == 0) {
        float* zr = zp + ((size_t)((p << 11) + i) << 8) + cl * 8;
        *(float4*)(zr) = make_float4(aY0, aY1, aX0, aX1);
        *(float4*)(zr + 4) = make_float4(aY2, aY3, aX2, aX3);
    }
}

// ---------------- reduce partials + fused output matvecs ----------------
__global__ __launch_bounds__(256) void k_reduce(const float* __restrict__ zp,
                                                const float* __restrict__ W2, const float* __restrict__ b2,
                                                const float* __restrict__ W3, const float* __restrict__ b3,
                                                float* __restrict__ out) {
    int i = blockIdx.x;   // node 0..2046
    int t = threadIdx.x;
    __shared__ float zm[128], zxm[128];
    float s = 0.f;
    #pragma unroll
    for (int p = 0; p < 8; ++p) s += zp[((size_t)((p << 11) + i) << 8) + t];
    s *= (1.0f / 64.0f);
    int k = t >> 2, r = t & 3;
    if (r < 2) zm[2 * k + r] = s; else zxm[2 * k + (r - 2)] = s;
    __syncthreads();
    int cc = t & 127;
    if (t < 128) {
        float acc = b2[cc];
        #pragma unroll 8
        for (int f = 0; f < 128; ++f) acc += zm[f] * W2[f * 128 + cc];
        out[i * 128 + cc] = acc;
    } else {
        float acc = b3[cc];
        #pragma unroll 8
        for (int f = 0; f < 128; ++f) acc += (zxm[f] - zm[f]) * W3[f * 128 + cc];
        out[2047 * 128 + i * 128 + cc] = acc;
    }
}

// ---------------- launch ----------------

extern "C" void kernel_launch(void* const* d_in, const int* in_sizes, int n_in,
                              void* d_out, int out_size, void* d_ws, size_t ws_size,
                              hipStream_t stream) {
    const float* x    = (const float*)d_in[0];
    const int* ei     = (const int*)d_in[1];
    const int* center = (const int*)d_in[3];
    const float* W1 = (const float*)d_in[4];
    const float* b1 = (const float*)d_in[5];
    const float* W2 = (const float*)d_in[6];
    const float* b2 = (const float*)d_in[7];
    const float* W3 = (const float*)d_in[8];
    const float* b3 = (const float*)d_in[9];
    const float* Wm = (const float*)d_in[10];
    const float* bm = (const float*)d_in[11];
    float* out = (float*)d_out;

    char* ws = (char*)d_ws;
    int*   degc   = (int*)(ws + 0);            // 512 KB
    float* dis    = (float*)(ws + 524288);     // 512 KB
    float* invdeg = (float*)(ws + 1048576);    // 512 KB
    int*   rp     = (int*)(ws + 1572864);      // 512 KB (per-graph CSR row starts)
    float* A      = (float*)(ws + 2097152);    // 32 KB
    u16*   Wtp    = (u16*)(ws + 2129920);      // 32 KB
    int2*  nme    = (int2*)(ws + 2162688);     // 8 MB
    float* zp     = (float*)(ws + 10551296);   // 16 MB
    u16*   xy     = (u16*)(ws + 27328512);     // 67 MB  (end ~94.4 MB)

    k_hist<<<dim3(Gg), dim3(1024), 0, stream>>>(ei, degc, dis, invdeg);
    k_scan_g<<<dim3(Gg), dim3(1024), 0, stream>>>(degc, rp);
    k_scatter<<<dim3(Gg), dim3(1024), 0, stream>>>(ei, dis, rp, nme);
    k_trans<<<dim3(64), dim3(256), 0, stream>>>(Wm, Wtp);
    k_A<<<dim3(Gg), dim3(128), 0, stream>>>(x, center, invdeg, rp, degc, nme, W1, b1, Wm, bm, A);
    k_masky<<<dim3(2048), dim3(256), 0, stream>>>(x, Wtp, A, xy);
    k_propx<<<dim3(4096), dim3(256), 0, stream>>>(xy, invdeg, rp, degc, nme, zp);
    k_reduce<<<dim3(Nn - 1), dim3(256), 0, stream>>>(zp, W2, b2, W3, b3, out);
}